// Round 1
// baseline (69.988 us; speedup 1.0000x reference)
//
#include <hip/hip_runtime.h>
#include <math.h>

#define BM 64
#define BN 64
#define BK 32
#define B_TOT 2048
#define IN_TOT 512
#define OUT_TOT 512
#define LSTR 36          // 32 + 4 pad: keeps 16B alignment, spreads bank groups
#define NTILES (IN_TOT / BK)

__global__ __launch_bounds__(256) void morph_kernel(
    const float* __restrict__ x,
    const float* __restrict__ wdil,
    const float* __restrict__ wero,
    float* __restrict__ out)
{
    __shared__ float sx[2][BM * LSTR];
    __shared__ float sd[2][BN * LSTR];
    __shared__ float se[2][BN * LSTR];

    const int tid = (int)threadIdx.x;
    const int tx = tid & 15;   // -> output cols {tx, tx+16, tx+32, tx+48}
    const int ty = tid >> 4;   // -> output rows {ty, ty+16, ty+32, ty+48}

    const int brow0 = (int)blockIdx.y * BM;
    const int bcol0 = (int)blockIdx.x * BN;

    // staging: each thread loads 2 float4 per array per K-tile
    const int srow = tid >> 3;   // 0..31
    const int sj   = tid & 7;    // 0..7  (float4 index within 32-float K-chunk)

    const size_t xoff0 = (size_t)(brow0 + srow) * IN_TOT + sj * 4;
    const size_t xoff1 = xoff0 + (size_t)32 * IN_TOT;
    const size_t woff0 = (size_t)(bcol0 + srow) * IN_TOT + sj * 4;
    const size_t woff1 = woff0 + (size_t)32 * IN_TOT;

    const int l0 = srow * LSTR + sj * 4;
    const int l1 = (srow + 32) * LSTR + sj * 4;

    float4 rx0, rx1, rd0, rd1, re0, re1;

    // ---- prologue: stage K-tile 0 ----
    rx0 = *(const float4*)(x    + xoff0);
    rx1 = *(const float4*)(x    + xoff1);
    rd0 = *(const float4*)(wdil + woff0);
    rd1 = *(const float4*)(wdil + woff1);
    re0 = *(const float4*)(wero + woff0);
    re1 = *(const float4*)(wero + woff1);

    *(float4*)&sx[0][l0] = rx0;
    *(float4*)&sx[0][l1] = rx1;
    *(float4*)&sd[0][l0] = rd0;
    *(float4*)&sd[0][l1] = rd1;
    *(float4*)&se[0][l0] = re0;
    *(float4*)&se[0][l1] = re1;

    __syncthreads();

    float dil[4][4], ero[4][4];
#pragma unroll
    for (int m = 0; m < 4; ++m)
#pragma unroll
        for (int n = 0; n < 4; ++n) {
            dil[m][n] = -INFINITY;
            ero[m][n] =  INFINITY;
        }

#pragma unroll 1
    for (int t = 0; t < NTILES; ++t) {
        const int cur = t & 1;

        // issue next tile's global loads early; latency hides under compute
        if (t + 1 < NTILES) {
            const int k0 = (t + 1) * BK;
            rx0 = *(const float4*)(x    + xoff0 + k0);
            rx1 = *(const float4*)(x    + xoff1 + k0);
            rd0 = *(const float4*)(wdil + woff0 + k0);
            rd1 = *(const float4*)(wdil + woff1 + k0);
            re0 = *(const float4*)(wero + woff0 + k0);
            re1 = *(const float4*)(wero + woff1 + k0);
        }

        const float* __restrict__ xb = sx[cur];
        const float* __restrict__ db = sd[cur];
        const float* __restrict__ eb = se[cur];

#pragma unroll
        for (int kk = 0; kk < BK; kk += 4) {
            float4 xv[4], dv[4], ev[4];
#pragma unroll
            for (int m = 0; m < 4; ++m)
                xv[m] = *(const float4*)&xb[(ty + 16 * m) * LSTR + kk];
#pragma unroll
            for (int n = 0; n < 4; ++n) {
                dv[n] = *(const float4*)&db[(tx + 16 * n) * LSTR + kk];
                ev[n] = *(const float4*)&eb[(tx + 16 * n) * LSTR + kk];
            }
#pragma unroll
            for (int m = 0; m < 4; ++m)
#pragma unroll
                for (int n = 0; n < 4; ++n) {
                    float a0 = xv[m].x + dv[n].x;
                    float a1 = xv[m].y + dv[n].y;
                    float a2 = xv[m].z + dv[n].z;
                    float a3 = xv[m].w + dv[n].w;
                    // fmaxf(fmaxf(a,b),acc) -> v_max3_f32
                    dil[m][n] = fmaxf(fmaxf(a0, a1), dil[m][n]);
                    dil[m][n] = fmaxf(fmaxf(a2, a3), dil[m][n]);
                    float s0 = xv[m].x - ev[n].x;
                    float s1 = xv[m].y - ev[n].y;
                    float s2 = xv[m].z - ev[n].z;
                    float s3 = xv[m].w - ev[n].w;
                    ero[m][n] = fminf(fminf(s0, s1), ero[m][n]);
                    ero[m][n] = fminf(fminf(s2, s3), ero[m][n]);
                }
        }

        // write prefetched tile into the other buffer (after compute)
        if (t + 1 < NTILES) {
            const int nxt = cur ^ 1;
            *(float4*)&sx[nxt][l0] = rx0;
            *(float4*)&sx[nxt][l1] = rx1;
            *(float4*)&sd[nxt][l0] = rd0;
            *(float4*)&sd[nxt][l1] = rd1;
            *(float4*)&se[nxt][l0] = re0;
            *(float4*)&se[nxt][l1] = re1;
        }
        __syncthreads();
    }

    // epilogue: out = dil + ero
#pragma unroll
    for (int m = 0; m < 4; ++m) {
        const int r = brow0 + ty + 16 * m;
#pragma unroll
        for (int n = 0; n < 4; ++n) {
            const int c = bcol0 + tx + 16 * n;
            out[(size_t)r * OUT_TOT + c] = dil[m][n] + ero[m][n];
        }
    }
}

extern "C" void kernel_launch(void* const* d_in, const int* in_sizes, int n_in,
                              void* d_out, int out_size, void* d_ws, size_t ws_size,
                              hipStream_t stream)
{
    const float* x  = (const float*)d_in[0];
    const float* wd = (const float*)d_in[1];
    const float* we = (const float*)d_in[2];
    float* out = (float*)d_out;

    dim3 grid(OUT_TOT / BN, B_TOT / BM);   // (8, 32) = 256 blocks, 1 per CU
    dim3 block(256);
    hipLaunchKernelGGL(morph_kernel, grid, block, 0, stream, x, wd, we, out);
}